// Round 7
// baseline (2947.745 us; speedup 1.0000x reference)
//
#include <hip/hip_runtime.h>
#include <math.h>

#define SS 512
#define AANG 60
#define DDET 729
#define NPIX (SS*SS)        // 262144
#define NSIN (AANG*DDET)    // 43740
#define NTAPS 1457
#define NQ 183              // detector quads per angle (183*4 = 732 >= 729)

typedef float v4u __attribute__((ext_vector_type(4), aligned(4)));
typedef float v4a __attribute__((ext_vector_type(4), aligned(16)));
typedef float v2u __attribute__((ext_vector_type(2), aligned(8)));
typedef float v2a __attribute__((ext_vector_type(2), aligned(4)));

// ---------------- trig table: ca[60], sa[60] ----------------
__global__ void trig_kernel(const float* __restrict__ theta, float* __restrict__ trig){
  int a = threadIdx.x;
  if (a < AANG){ trig[a] = cosf(theta[a]); trig[AANG+a] = sinf(theta[a]); }
}

// ---------------- ramp-filter taps (exact irfft of 2*rfftfreq(2048), folded pi/120) --------
__global__ void taps_kernel(float* __restrict__ taps){
  __shared__ double red[256];
  int m  = blockIdx.x;      // 0..1456
  int mm = m - 728;         // -728..728
  double s = 0.0;
  for (int k = 1 + (int)threadIdx.x; k <= 1023; k += 256){
    int phase = (k*mm) & 2047;
    s += (double)k * cos((double)phase * (M_PI/1024.0));
  }
  red[threadIdx.x] = s;
  __syncthreads();
  for (int off=128; off; off>>=1){
    if ((int)threadIdx.x < off) red[threadIdx.x] += red[threadIdx.x+off];
    __syncthreads();
  }
  if (threadIdx.x==0){
    double x = (red[0]*(1.0/512.0) + ((mm & 1) ? -1.0 : 1.0)) / 2048.0;
    taps[m] = (float)(x * (M_PI/120.0));
  }
}

// ---------------- legacy transposes (conv3 layers): -> [L][Cin][9][Cout] ----------------
__global__ void transpose_all(const float* __restrict__ s2, float* __restrict__ d2,
                              const float* __restrict__ s5, float* __restrict__ d5){
  int idx = blockIdx.x*256 + (int)threadIdx.x;
  const float* src; float* dst;
  int Cout = 5, Cin = 32;
  if      (idx < 14400){              src=s2; dst=d2; }
  else if (idx < 28800){ idx-=14400;  src=s5; dst=d5; }
  else return;
  int t = idx % 9; int r = idx/9;
  int i = r % Cin; r /= Cin;
  int o = r % Cout; int l = r/Cout;
  dst[((l*Cin+i)*9+t)*Cout+o] = src[idx];
}

// ---------------- cg-split re-layout: [L][O=32][Cin][3][3] -> [L][Cin][cg=4][t=9][u=8] ----------
__global__ void transpose_w8(const float* __restrict__ src, float* __restrict__ dst, int Cin){
  int idx = blockIdx.x*256 + (int)threadIdx.x;
  int tot = 10*32*Cin*9;
  if (idx >= tot) return;
  int t = idx % 9; int r = idx/9;
  int i = r % Cin; r /= Cin;
  int o = r % 32; int l = r/32;
  int cg = o >> 3, u = o & 7;
  dst[(((l*Cin + i)*4 + cg)*9 + t)*8 + u] = src[idx];
}

// ---------------- radon forward: 4 detectors per wave ----------------
__device__ inline void clipr(float al, float be, float lo, float hi,
                             float& A, float& B, bool& empty){
  if (fabsf(al) < 1e-7f){ if (be < lo || be > hi) empty = true; return; }
  float t0 = (lo - be)/al, t1 = (hi - be)/al;
  float mn = fminf(t0,t1), mx = fmaxf(t0,t1);
  A = fmaxf(A, mn); B = fminf(B, mx);
}

__device__ inline float samp_guard(const float* __restrict__ base, float aR, float bR,
                                   float aC, float bC, int t){
  float tp = (float)t - 255.5f;
  float R = fmaf(aR, tp, bR);
  float C = fmaf(aC, tp, bC);
  float rf = floorf(R), cf = floorf(C);
  int r0 = (int)rf, c0 = (int)cf;
  int r1 = r0+1,    c1 = c0+1;
  float fr = R - rf, fc = C - cf;
  bool r0ok = (r0>=0 && r0<SS), r1ok = (r1>=0 && r1<SS);
  bool c0ok = (c0>=0 && c0<SS), c1ok = (c1>=0 && c1<SS);
  float v00 = (r0ok && c0ok) ? base[r0*SS+c0] : 0.f;
  float v01 = (r0ok && c1ok) ? base[r0*SS+c1] : 0.f;
  float v10 = (r1ok && c0ok) ? base[r1*SS+c0] : 0.f;
  float v11 = (r1ok && c1ok) ? base[r1*SS+c1] : 0.f;
  return (1.f-fr)*((1.f-fc)*v00 + fc*v01) + fr*((1.f-fc)*v10 + fc*v11);
}

__global__ __launch_bounds__(256) void radon_fwd_quad(
    const float* __restrict__ img, const float* __restrict__ imgT,
    const float* __restrict__ trig, float* __restrict__ out){
  int gid  = blockIdx.x*4 + ((int)threadIdx.x >> 6);
  int lane = (int)threadIdx.x & 63;
  if (gid >= AANG*NQ) return;
  int a  = gid / NQ;
  int dq = gid - a*NQ;
  int d0 = dq*4;
  float ca = trig[a], sa = trig[AANG+a];
  float sd = (float)d0 - 364.0f;
  // img frame: row = sa*sd + ca*tp + 255.5 ; col = ca*sd - sa*tp + 255.5
  float aR = ca,  bR = fmaf(sd, sa, 255.5f), dR = sa;
  float aC = -sa, bC = fmaf(sd, ca, 255.5f), dC = ca;
  const float* base = img;
  if (fabsf(ca) > fabsf(sa)){
    base = imgT;
    float t;
    t=aR; aR=aC; aC=t;
    t=bR; bR=bC; bC=t;
    t=dR; dR=dC; dC=t;
  }
  // union of exterior ranges / intersection of interior ranges over the 4 d's
  float uA = 1e9f, uB = -1e9f;
  float iA = -255.5f, iB = 255.5f; bool iOK = true;
  #pragma unroll
  for (int j=0;j<4;j++){
    float bRj = bR + (float)j*dR, bCj = bC + (float)j*dC;
    float A=-255.5f, B=255.5f; bool E=false;
    clipr(aR,bRj, -0.999f, 511.999f, A,B,E);
    clipr(aC,bCj, -0.999f, 511.999f, A,B,E);
    if (!E && A<=B){ uA = fminf(uA,A); uB = fmaxf(uB,B); }
    float A2=-255.5f, B2=255.5f; bool E2=false;
    clipr(aR,bRj, 0.001f, 510.999f, A2,B2,E2);
    clipr(aC,bCj, 0.001f, 510.999f, A2,B2,E2);
    if (E2) iOK = false;
    else { iA = fmaxf(iA,A2); iB = fminf(iB,B2); }
  }
  float accq[4] = {0.f,0.f,0.f,0.f};
  if (uB >= uA){
    int eA = max(0,   (int)floorf(uA+255.5f) - 1);
    int eB = min(511, (int)ceilf (uB+255.5f) + 1);
    int jA = 1, jB = 0;
    if (iOK && iA <= iB){
      jA = (int)ceilf (iA+255.5f) + 1;
      jB = (int)floorf(iB+255.5f) - 1;
      jA = max(jA, eA); jB = min(jB, eB);
    }
    if (jA > jB){
      for (int t = eA+lane; t <= eB; t += 64){
        #pragma unroll
        for (int j=0;j<4;j++)
          accq[j] += samp_guard(base, aR, bR+(float)j*dR, aC, bC+(float)j*dC, t);
      }
    } else {
      for (int t = eA+lane; t < jA; t += 64){
        #pragma unroll
        for (int j=0;j<4;j++)
          accq[j] += samp_guard(base, aR, bR+(float)j*dR, aC, bC+(float)j*dC, t);
      }
      for (int t = jB+1+lane; t <= eB; t += 64){
        #pragma unroll
        for (int j=0;j<4;j++)
          accq[j] += samp_guard(base, aR, bR+(float)j*dR, aC, bC+(float)j*dC, t);
      }
      for (int t = jA+lane; t <= jB; t += 64){
        float tp = (float)t - 255.5f;
        float R0 = fmaf(aR, tp, bR);
        float C0 = fmaf(aC, tp, bC);
        #pragma unroll
        for (int j=0;j<4;j++){
          float R = R0 + (float)j*dR;
          float C = C0 + (float)j*dC;
          int r0 = (int)R, c0 = (int)C;      // interior: trunc == floor
          float fr = R - (float)r0, fc = C - (float)c0;
          const float* p = base + (r0<<9) + c0;
          float v00 = p[0], v01 = p[1], v10 = p[SS], v11 = p[SS+1];
          float top = v00 + fc*(v01-v00);
          float bot = v10 + fc*(v11-v10);
          accq[j] += top + fr*(bot-top);
        }
      }
    }
  }
  #pragma unroll
  for (int j=0;j<4;j++)
    for (int off=32; off; off>>=1) accq[j] += __shfl_down(accq[j], off);
  if (lane==0){
    #pragma unroll
    for (int j=0;j<4;j++)
      if (d0+j < DDET) out[a*DDET + d0 + j] = accq[j];
  }
}

// ---------------- ramp filter ----------------
__global__ void filter_kernel(const float* __restrict__ h0, const float* __restrict__ taps,
                              float* __restrict__ h1){
  int gid = blockIdx.x*blockDim.x + threadIdx.x;
  if (gid >= NSIN) return;
  int a = gid / DDET;
  int j = gid - a*DDET;
  const float* row = h0 + a*DDET;
  float acc = 0.f;
  for (int k=0;k<DDET;k++){
    acc += row[k] * taps[728 + j - k];
  }
  h1[gid] = acc;
}

// ---------------- backprojection with LDS-staged detector windows ----------------
__global__ __launch_bounds__(256) void backproj_kernel(
    const float* __restrict__ h1, const float* __restrict__ trig,
    float* __restrict__ out){
  __shared__ float sh[AANG*28];
  __shared__ int   sbase[AANG];
  __shared__ float strig[2*AANG];
  int tid = threadIdx.x;
  int x0 = (blockIdx.x & 31) * 16, y0 = (blockIdx.x >> 5) * 16;
  if (tid < 2*AANG) strig[tid] = trig[tid];
  __syncthreads();
  if (tid < AANG){
    float ca = strig[tid], sa = strig[AANG+tid];
    float Xa = (float)x0 - 255.5f, Xb = Xa + 15.f;
    float Ya = (float)y0 - 255.5f, Yb = Ya + 15.f;
    float s00 = Xa*ca + Ya*sa, s01 = Xb*ca + Ya*sa;
    float s10 = Xa*ca + Yb*sa, s11 = Xb*ca + Yb*sa;
    float mn = fminf(fminf(s00,s01), fminf(s10,s11)) + 364.0f;
    sbase[tid] = (int)floorf(mn) - 2;
  }
  __syncthreads();
  for (int s = tid; s < AANG*28; s += 256){
    int a = s / 28, j = s - a*28;
    int idx = sbase[a] + j;
    sh[s] = (idx >= 0 && idx < DDET) ? h1[a*DDET + idx] : 0.f;
  }
  __syncthreads();
  int x = x0 + (tid & 15), y = y0 + (tid >> 4);
  float X = (float)x - 255.5f, Y = (float)y - 255.5f;
  float acc = 0.f;
  #pragma unroll 6
  for (int a=0;a<AANG;a++){
    float sidx = fmaf(X, strig[a], fmaf(Y, strig[AANG+a], 364.0f));
    float ff = floorf(sidx);
    int k = (int)ff - sbase[a];
    float fi = sidx - ff;
    float v0 = sh[a*28+k], v1 = sh[a*28+k+1];
    acc += v0 + fi*(v1-v0);
  }
  out[y*SS+x] = acc;
}

// ---------------- dual conv, cg-split + LDS weights + pixel prefetch ----------------
// grid (171, 4); input = NCH contiguous channels; weights [cin][cg=4][9][8]
template<int NCH>
__global__ __launch_bounds__(256) void conv3x3_dualcg(
    const float* __restrict__ in,
    const float* __restrict__ wt,
    const float* __restrict__ bias, const float* __restrict__ prelu,
    float* __restrict__ out)
{
  __shared__ float sw[NCH*288];
  int tid = (int)threadIdx.x;
  for (int t = tid; t < NCH*288; t += 256) sw[t] = wt[t];
  __syncthreads();
  const int W = DDET, HW = NSIN;
  int pix = blockIdx.x*256 + tid;
  if (pix >= NSIN) return;
  int cg = blockIdx.y;
  int y = pix / W, x = pix - y*W;
  bool ym = y>0, yp = y<AANG-1, xm = x>0, xp = x<W-1;
  float acc[8];
  #pragma unroll
  for (int o=0;o<8;o++) acc[o] = bias[cg*8+o];
  const float* swc = sw + cg*72;
  const float* ip = in + pix;
  float p[9];
  {
    p[4] = ip[0];
    p[0]=0;p[1]=0;p[2]=0;p[3]=0;p[5]=0;p[6]=0;p[7]=0;p[8]=0;
    if (ym){ p[1] = ip[-W]; if (xm) p[0] = ip[-W-1]; if (xp) p[2] = ip[-W+1]; }
    if (xm) p[3] = ip[-1];
    if (xp) p[5] = ip[1];
    if (yp){ p[7] = ip[W]; if (xm) p[6] = ip[W-1]; if (xp) p[8] = ip[W+1]; }
  }
  for (int i=0;i<NCH;i++){
    const float* ipn = ip + HW;
    bool more = (i+1) < NCH;
    float pn[9];
    pn[0]=0;pn[1]=0;pn[2]=0;pn[3]=0;pn[4]=0;pn[5]=0;pn[6]=0;pn[7]=0;pn[8]=0;
    if (more){
      pn[4] = ipn[0];
      if (ym){ pn[1] = ipn[-W]; if (xm) pn[0] = ipn[-W-1]; if (xp) pn[2] = ipn[-W+1]; }
      if (xm) pn[3] = ipn[-1];
      if (xp) pn[5] = ipn[1];
      if (yp){ pn[7] = ipn[W]; if (xm) pn[6] = ipn[W-1]; if (xp) pn[8] = ipn[W+1]; }
    }
    const float* wp = swc + i*288;
    #pragma unroll
    for (int t=0;t<9;t++){
      float v = p[t];
      #pragma unroll
      for (int o=0;o<8;o++) acc[o] = fmaf(v, wp[t*8+o], acc[o]);
    }
    #pragma unroll
    for (int t=0;t<9;t++) p[t] = pn[t];
    ip = ipn;
  }
  float aa = *prelu;
  float* op = out + (size_t)(cg*8)*HW + pix;
  #pragma unroll
  for (int o=0;o<8;o++){
    float s = acc[o];
    s = (s>=0.f) ? s : aa*s;
    op[o*HW] = s;
  }
}

// ---------------- dual conv3 (32->5): 1 px/thread, accumulate into h ----------------
template<int COUT, int W>
__global__ __launch_bounds__(256) void conv3x3_fast(
    const float* __restrict__ in1, int Cin1,
    const float* __restrict__ wt,
    const float* __restrict__ bias,
    float* __restrict__ out, int H)
{
  int HW = H*W;
  int pix = blockIdx.x*256 + (int)threadIdx.x;
  if (pix >= HW) return;
  int y = pix / W, x = pix - y*W;
  bool ym = y>0, yp = y<H-1, xm = x>0, xp = x<W-1;
  float acc[COUT];
  #pragma unroll
  for (int o=0;o<COUT;o++) acc[o] = bias[o];
  const float* wr = wt;
  const float* ip = in1 + pix;
  for (int i=0;i<Cin1;i++, ip+=HW){
    float p4 = ip[0];
    float p0=0,p1=0,p2=0,p3=0,p5=0,p6=0,p7=0,p8=0;
    if (ym){ p1 = ip[-W]; if (xm) p0 = ip[-W-1]; if (xp) p2 = ip[-W+1]; }
    if (xm) p3 = ip[-1];
    if (xp) p5 = ip[1];
    if (yp){ p7 = ip[W]; if (xm) p6 = ip[W-1]; if (xp) p8 = ip[W+1]; }
    float p[9] = {p0,p1,p2,p3,p4,p5,p6,p7,p8};
    #pragma unroll
    for (int t=0;t<9;t++){
      float v = p[t];
      #pragma unroll
      for (int o=0;o<COUT;o++) acc[o] = fmaf(v, wr[t*COUT+o], acc[o]);
    }
    wr += 9*COUT;
  }
  float* op = out + pix;
  #pragma unroll
  for (int o=0;o<COUT;o++) op[o*HW] += acc[o];
}

// ---------------- primal conv quad: 4 px x 8 outs, LDS weights, pixel prefetch ----------
__device__ inline void ldrow(v4u& A, v2a& B, const float* p, bool valid){
  if (valid){ A = *(const v4u*)(p-1); B = *(const v2a*)(p+3); }
  else { A = (v4u)0.f; B = (v2a)0.f; }
}
__device__ inline void expand6(float* R, v4u A, v2a B, bool lE, bool rE){
  R[0] = lE ? 0.f : A.x; R[1]=A.y; R[2]=A.z; R[3]=A.w;
  R[4] = B.x; R[5] = rE ? 0.f : B.y;
}

template<int NCH>
__global__ __launch_bounds__(256) void conv3x3_quad(
    const float* __restrict__ in,
    const float* __restrict__ wt,      // [cin][4][9][8]
    const float* __restrict__ bias, const float* __restrict__ prelu,
    float* __restrict__ out)
{
  __shared__ float sw[NCH*288];
  int tid = (int)threadIdx.x;
  for (int t = tid; t < NCH*288; t += 256) sw[t] = wt[t];
  __syncthreads();
  const int W = SS, HW = NPIX;
  int rb = blockIdx.x;                       // 0..255 row-pairs
  int cg = blockIdx.y;                       // 0..3
  int yb = ((rb & 7) << 5) | (rb >> 3);      // XCD swizzle
  int wv = tid >> 6;
  int lane = tid & 63;
  int y = yb*2 + (wv >> 1);
  int xb = ((wv & 1) << 8) + lane*4;         // 0..508
  const float* swc = sw + cg*72;
  float acc[4][8];
  #pragma unroll
  for (int px=0;px<4;px++)
    #pragma unroll
    for (int o=0;o<8;o++) acc[px][o] = 0.f;
  bool ym = y>0, yp = y<SS-1;                // wave-uniform
  bool lE = (xb==0), rE = (xb==508);
  const float* ip = in + y*W + xb;
  v4u A0,A1,A2; v2a B0,B1,B2;
  ldrow(A0,B0, ip-W, ym);
  ldrow(A1,B1, ip,   true);
  ldrow(A2,B2, ip+W, yp);
  for (int i=0;i<NCH;i++){
    const float* ipn = ip + HW;
    bool more = (i+1) < NCH;
    v4u N0,N1,N2; v2a M0,M1,M2;
    ldrow(N0,M0, ipn-W, ym && more);
    ldrow(N1,M1, ipn,   more);
    ldrow(N2,M2, ipn+W, yp && more);
    float R[3][6];
    expand6(R[0], A0,B0, lE,rE);
    expand6(R[1], A1,B1, lE,rE);
    expand6(R[2], A2,B2, lE,rE);
    const float* wp = swc + i*288;
    #pragma unroll
    for (int dy=0;dy<3;dy++){
      #pragma unroll
      for (int dx=0;dx<3;dx++){
        #pragma unroll
        for (int o=0;o<8;o++){
          float w = wp[(dy*3+dx)*8+o];
          #pragma unroll
          for (int px=0;px<4;px++)
            acc[px][o] = fmaf(R[dy][px+dx], w, acc[px][o]);
        }
      }
    }
    A0=N0; A1=N1; A2=N2; B0=M0; B1=M1; B2=M2;
    ip = ipn;
  }
  float aa = *prelu;
  float* op = out + (size_t)(cg*8)*HW + y*W + xb;
  #pragma unroll
  for (int o=0;o<8;o++){
    float bv = bias[cg*8+o];
    v4a s;
    s.x=acc[0][o]+bv; s.y=acc[1][o]+bv; s.z=acc[2][o]+bv; s.w=acc[3][o]+bv;
    s.x=(s.x>=0.f)?s.x:aa*s.x; s.y=(s.y>=0.f)?s.y:aa*s.y;
    s.z=(s.z>=0.f)?s.z:aa*s.z; s.w=(s.w>=0.f)?s.w:aa*s.w;
    *(v4a*)(op + o*HW) = s;
  }
}

// ---------------- primal conv3 (32->5): one row per block, 2 px/thread ----------------
template<int COUT>
__global__ __launch_bounds__(256) void conv3x3_duo(
    const float* __restrict__ in1, int Cin1,
    const float* __restrict__ wt,
    const float* __restrict__ bias,
    float* __restrict__ out,
    float* __restrict__ fout, float* __restrict__ tout)
{
  const int W = SS, HW = NPIX;
  int b = blockIdx.x;
  int y = ((b & 7) << 6) | (b >> 3);      // row-stripe per XCD
  int x0 = (int)threadIdx.x * 2;
  int pix0 = y*W + x0;
  bool ym = y > 0, yp = y < SS-1;
  bool l0 = x0 > 0;
  bool r3 = x0 + 2 < W;
  float acc0[COUT], acc1[COUT];
  #pragma unroll
  for (int o=0;o<COUT;o++){ float bv = bias[o]; acc0[o]=bv; acc1[o]=bv; }
  const float* wr = wt;
  const float* ip = in1 + pix0;
  #pragma unroll 2
  for (int i=0;i<Cin1;i++, ip+=HW){
    v4u A = ym ? *(const v4u*)(ip - W - 1) : (v4u)0.f;
    v4u B = *(const v4u*)(ip - 1);
    v4u D = yp ? *(const v4u*)(ip + W - 1) : (v4u)0.f;
    if (!l0){ A.x = 0.f; B.x = 0.f; D.x = 0.f; }
    if (!r3){ A.w = 0.f; B.w = 0.f; D.w = 0.f; }
    float w0[9] = {A.x,A.y,A.z, B.x,B.y,B.z, D.x,D.y,D.z};
    float w1[9] = {A.y,A.z,A.w, B.y,B.z,B.w, D.y,D.z,D.w};
    #pragma unroll
    for (int t=0;t<9;t++){
      float v0 = w0[t], v1 = w1[t];
      #pragma unroll
      for (int o=0;o<COUT;o++){
        float w = wr[t*COUT+o];
        acc0[o] = fmaf(v0, w, acc0[o]);
        acc1[o] = fmaf(v1, w, acc1[o]);
      }
    }
    wr += 9*COUT;
  }
  float* op = out + pix0;
  #pragma unroll
  for (int o=0;o<COUT;o++){
    float s0 = acc0[o], s1 = acc1[o];
    v2u old = *(const v2u*)(op + o*HW);
    s0 += old.x; s1 += old.y;
    v2u st; st.x = s0; st.y = s1;
    *(v2u*)(op + o*HW) = st;
    if (o==1 && tout){ tout[x0*SS + y] = s0; tout[(x0+1)*SS + y] = s1; }
    if (o==0 && fout){
      *(v2u*)(fout + pix0) = st;
      *(v2u*)(fout + HW + pix0) = st;
      *(v2u*)(fout + 2*HW + pix0) = st;
    }
  }
}

extern "C" void kernel_launch(void* const* d_in, const int* in_sizes, int n_in,
                              void* d_out, int out_size, void* d_ws, size_t ws_size,
                              hipStream_t stream){
  const float* g     = (const float*)d_in[2];
  const float* theta = (const float*)d_in[3];
  const float* dw1 = (const float*)d_in[5];
  const float* db1 = (const float*)d_in[6];
  const float* da1 = (const float*)d_in[7];
  const float* dw2 = (const float*)d_in[8];
  const float* db2 = (const float*)d_in[9];
  const float* da2 = (const float*)d_in[10];
  const float* dw3 = (const float*)d_in[11];
  const float* db3 = (const float*)d_in[12];
  const float* pw1 = (const float*)d_in[13];
  const float* pb1 = (const float*)d_in[14];
  const float* pa1 = (const float*)d_in[15];
  const float* pw2 = (const float*)d_in[16];
  const float* pb2 = (const float*)d_in[17];
  const float* pa2 = (const float*)d_in[18];
  const float* pw3 = (const float*)d_in[19];
  const float* pb3 = (const float*)d_in[20];

  float* ws     = (float*)d_ws;
  float* trig   = ws;                  // 128
  float* taps   = ws + 128;            // 1457 (region to 2048)
  // dual input block, channel-contiguous: [h(5) | opf | g]
  float* h      = ws + 2048;           // 5*NSIN
  float* opf    = h + 5*NSIN;          // NSIN
  float* gcopy  = opf + NSIN;          // NSIN
  float* h1     = gcopy + NSIN;        // NSIN
  // primal input block, channel-contiguous: [f(5) | bp]
  float* f      = h1 + NSIN;           // 5*NPIX
  float* bp     = f + 5*NPIX;          // NPIX
  float* imgT   = bp + NPIX;           // NPIX
  float* primT1 = imgT + NPIX;         // 32*NPIX
  float* primT2 = primT1 + 32*NPIX;    // 32*NPIX
  float* dualT1 = primT1;              // aliased, lifetimes disjoint
  float* dualT2 = dualT1 + 32*NSIN;
  float* wsp   = primT2 + 32*NPIX;
  float* wtd3  = wsp;                  // 14400 legacy [cin][9][5]
  float* wtp3  = wsp + 14400;          // 14400 legacy [cin][9][5]
  float* wtd1b = wsp + 28800;          // 20160 cg layout [l][7][4][9][8]
  float* wtd2b = wsp + 48960;          // 92160 cg layout [l][32][4][9][8]
  float* wtp1b = wsp + 141120;         // 17280 cg layout [l][6][4][9][8]
  float* wtp2b = wsp + 158400;         // 92160 cg layout [l][32][4][9][8]

  // zero h (5*NSIN) and f..imgT (7*NPIX covers f, bp, imgT)
  hipMemsetAsync(h, 0, (size_t)(5*NSIN)*sizeof(float), stream);
  hipMemsetAsync(f, 0, (size_t)(7*NPIX)*sizeof(float), stream);
  hipMemcpyAsync(gcopy, g, (size_t)NSIN*sizeof(float), hipMemcpyDeviceToDevice, stream);
  trig_kernel<<<1,64,0,stream>>>(theta, trig);
  taps_kernel<<<NTAPS,256,0,stream>>>(taps);
  transpose_all<<<(28800+255)/256,256,0,stream>>>(dw3,wtd3, pw3,wtp3);
  transpose_w8<<<(20160+255)/256,256,0,stream>>>(dw1, wtd1b, 7);
  transpose_w8<<<(92160+255)/256,256,0,stream>>>(dw2, wtd2b, 32);
  transpose_w8<<<(17280+255)/256,256,0,stream>>>(pw1, wtp1b, 6);
  transpose_w8<<<(92160+255)/256,256,0,stream>>>(pw2, wtp2b, 32);

  const int GD = (NSIN+255)/256;       // 171
  const int GR = (AANG*NQ+3)/4;        // 2745

  for (int i=0;i<10;i++){
    radon_fwd_quad<<<GR,256,0,stream>>>(f + NPIX, imgT, trig, opf);
    // dual block: in = [h(5) | opf | g] contiguous
    conv3x3_dualcg<7><<<dim3(GD,4),256,0,stream>>>(h,      wtd1b+(size_t)i*7*288,  db1+(size_t)i*32, da1+i, dualT1);
    conv3x3_dualcg<32><<<dim3(GD,4),256,0,stream>>>(dualT1, wtd2b+(size_t)i*32*288, db2+(size_t)i*32, da2+i, dualT2);
    conv3x3_fast<5,DDET><<<GD,256,0,stream>>>(dualT2, 32, wtd3+i*32*9*5, db3+(size_t)i*5, h, AANG);
    filter_kernel<<<GD,256,0,stream>>>(h, taps, h1);
    backproj_kernel<<<NPIX/256,256,0,stream>>>(h1, trig, bp);
    // primal block: in = [f(5) | bp] contiguous
    conv3x3_quad<6><<<dim3(256,4),256,0,stream>>>(f,      wtp1b+(size_t)i*6*288,  pb1+(size_t)i*32, pa1+i, primT1);
    conv3x3_quad<32><<<dim3(256,4),256,0,stream>>>(primT1, wtp2b+(size_t)i*32*288, pb2+(size_t)i*32, pa2+i, primT2);
    conv3x3_duo<5><<<SS,256,0,stream>>>(primT2, 32, wtp3+i*32*9*5, pb3+(size_t)i*5, f,
                                        (i==9) ? (float*)d_out : nullptr, imgT);
  }
}

// Round 8
// 2320.433 us; speedup vs baseline: 1.2703x; 1.2703x over previous
//
#include <hip/hip_runtime.h>
#include <math.h>

#define SS 512
#define AANG 60
#define DDET 729
#define NPIX (SS*SS)        // 262144
#define NSIN (AANG*DDET)    // 43740
#define NTAPS 1457

typedef float v4u __attribute__((ext_vector_type(4), aligned(4)));
typedef float v4a __attribute__((ext_vector_type(4), aligned(16)));
typedef float v2u __attribute__((ext_vector_type(2), aligned(8)));
typedef float v2a __attribute__((ext_vector_type(2), aligned(4)));
typedef short short8 __attribute__((ext_vector_type(8)));
typedef float f32x4 __attribute__((ext_vector_type(4)));

// round-to-nearest-even fp32 -> bf16 bits
__device__ inline unsigned short f2bf(float x){
  unsigned u = __float_as_uint(x);
  return (unsigned short)((u + 0x7fffu + ((u >> 16) & 1u)) >> 16);
}

// ---------------- trig table ----------------
__global__ void trig_kernel(const float* __restrict__ theta, float* __restrict__ trig){
  int a = threadIdx.x;
  if (a < AANG){ trig[a] = cosf(theta[a]); trig[AANG+a] = sinf(theta[a]); }
}

// ---------------- ramp-filter taps ----------------
__global__ void taps_kernel(float* __restrict__ taps){
  __shared__ double red[256];
  int m  = blockIdx.x;
  int mm = m - 728;
  double s = 0.0;
  for (int k = 1 + (int)threadIdx.x; k <= 1023; k += 256){
    int phase = (k*mm) & 2047;
    s += (double)k * cos((double)phase * (M_PI/1024.0));
  }
  red[threadIdx.x] = s;
  __syncthreads();
  for (int off=128; off; off>>=1){
    if ((int)threadIdx.x < off) red[threadIdx.x] += red[threadIdx.x+off];
    __syncthreads();
  }
  if (threadIdx.x==0){
    double x = (red[0]*(1.0/512.0) + ((mm & 1) ? -1.0 : 1.0)) / 2048.0;
    taps[m] = (float)(x * (M_PI/120.0));
  }
}

// ---------------- conv3 weight transposes: -> [L][Cin][9][5] ----------------
__global__ void transpose_all(const float* __restrict__ s2, float* __restrict__ d2,
                              const float* __restrict__ s5, float* __restrict__ d5){
  int idx = blockIdx.x*256 + (int)threadIdx.x;
  const float* src; float* dst;
  int Cout = 5, Cin = 32;
  if      (idx < 14400){              src=s2; dst=d2; }
  else if (idx < 28800){ idx-=14400;  src=s5; dst=d5; }
  else return;
  int t = idx % 9; int r = idx/9;
  int i = r % Cin; r /= Cin;
  int o = r % Cout; int l = r/Cout;
  dst[((l*Cin+i)*9+t)*Cout+o] = src[idx];
}

// ---------------- cg-split re-layout: [L][32][Cin][3][3] -> [L][Cin][4][9][8] ----------
__global__ void transpose_w8(const float* __restrict__ src, float* __restrict__ dst, int Cin){
  int idx = blockIdx.x*256 + (int)threadIdx.x;
  int tot = 10*32*Cin*9;
  if (idx >= tot) return;
  int t = idx % 9; int r = idx/9;
  int i = r % Cin; r /= Cin;
  int o = r % 32; int l = r/32;
  int cg = o >> 3, u = o & 7;
  dst[(((l*Cin + i)*4 + cg)*9 + t)*8 + u] = src[idx];
}

// -------- MFMA B-fragment image for pw2: [L][tap=9][n=2][prod=2][lane=64][8] bf16 --------
__global__ void prep_bimg(const float* __restrict__ w, unsigned short* __restrict__ B){
  int idx = blockIdx.x*256 + (int)threadIdx.x;
  if (idx >= 10*9*2*64*8) return;
  int j    =  idx        & 7;
  int lane = (idx >> 3)  & 63;
  int n    = (idx >> 9)  & 1;
  int r    =  idx >> 10;          // l*9 + tap
  int tap = r % 9, l = r / 9;
  int c = (lane >> 4)*8 + j;      // k = channel
  int o = n*16 + (lane & 15);     // output channel
  float x = w[(((size_t)(l*32+o)*32 + c)*9) + tap];
  unsigned short hb = f2bf(x);
  float hf = __uint_as_float((unsigned)hb << 16);
  unsigned short lb = f2bf(x - hf);
  size_t d = (size_t)l*18432 + (size_t)tap*2048 + n*1024 + lane*8 + j;
  B[d]       = hb;
  B[d + 512] = lb;
}

// ---------------- radon forward (R6-proven) ----------------
__device__ inline void clipr(float al, float be, float lo, float hi,
                             float& A, float& B, bool& empty){
  if (fabsf(al) < 1e-7f){ if (be < lo || be > hi) empty = true; return; }
  float t0 = (lo - be)/al, t1 = (hi - be)/al;
  float mn = fminf(t0,t1), mx = fmaxf(t0,t1);
  A = fmaxf(A, mn); B = fminf(B, mx);
}

__device__ inline float samp_guard(const float* __restrict__ base, float aR, float bR,
                                   float aC, float bC, int t){
  float tp = (float)t - 255.5f;
  float R = fmaf(aR, tp, bR);
  float C = fmaf(aC, tp, bC);
  float rf = floorf(R), cf = floorf(C);
  int r0 = (int)rf, c0 = (int)cf;
  int r1 = r0+1,    c1 = c0+1;
  float fr = R - rf, fc = C - cf;
  bool r0ok = (r0>=0 && r0<SS), r1ok = (r1>=0 && r1<SS);
  bool c0ok = (c0>=0 && c0<SS), c1ok = (c1>=0 && c1<SS);
  float v00 = (r0ok && c0ok) ? base[r0*SS+c0] : 0.f;
  float v01 = (r0ok && c1ok) ? base[r0*SS+c1] : 0.f;
  float v10 = (r1ok && c0ok) ? base[r1*SS+c0] : 0.f;
  float v11 = (r1ok && c1ok) ? base[r1*SS+c1] : 0.f;
  return (1.f-fr)*((1.f-fc)*v00 + fc*v01) + fr*((1.f-fc)*v10 + fc*v11);
}

__global__ __launch_bounds__(256) void radon_fwd_kernel(
    const float* __restrict__ img, const float* __restrict__ imgT,
    const float* __restrict__ trig, float* __restrict__ out){
  int gid  = blockIdx.x*4 + ((int)threadIdx.x >> 6);
  int lane = (int)threadIdx.x & 63;
  if (gid >= NSIN) return;
  int a = gid / DDET;
  int d = gid - a*DDET;
  float ca = trig[a], sa = trig[AANG+a];
  float sd = (float)d - 364.0f;
  float Rc = fmaf(sd, sa, 255.5f);
  float Cc = fmaf(sd, ca, 255.5f);
  float aR = ca, bR = Rc, aC = -sa, bC = Cc;
  const float* base = img;
  if (fabsf(ca) > fabsf(sa)){
    base = imgT;
    float tmp;
    tmp=aR; aR=aC; aC=tmp;
    tmp=bR; bR=bC; bC=tmp;
  }
  float tiA = -255.5f, tiB = 255.5f;  bool iE=false;
  float teA = -255.5f, teB = 255.5f;  bool eE=false;
  clipr(aR,bR, 0.001f, 510.999f, tiA,tiB,iE);
  clipr(aC,bC, 0.001f, 510.999f, tiA,tiB,iE);
  clipr(aR,bR, -0.999f, 511.999f, teA,teB,eE);
  clipr(aC,bC, -0.999f, 511.999f, teA,teB,eE);
  float acc = 0.f;
  if (!eE && teA <= teB){
    int eA = max(0,   (int)floorf(teA+255.5f) - 1);
    int eB = min(511, (int)ceilf (teB+255.5f) + 1);
    int iA = (int)ceilf (tiA+255.5f) + 1;
    int iB = (int)floorf(tiB+255.5f) - 1;
    iA = max(iA, eA); iB = min(iB, eB);
    if (iE || iA > iB){
      for (int t = eA+lane; t <= eB; t += 64) acc += samp_guard(base,aR,bR,aC,bC,t);
    } else {
      for (int t = eA+lane;   t <  iA; t += 64) acc += samp_guard(base,aR,bR,aC,bC,t);
      for (int t = iB+1+lane; t <= eB; t += 64) acc += samp_guard(base,aR,bR,aC,bC,t);
      for (int t = iA+lane;   t <= iB; t += 64){
        float tp = (float)t - 255.5f;
        float R = fmaf(aR, tp, bR);
        float C = fmaf(aC, tp, bC);
        int r0 = (int)R, c0 = (int)C;
        float fr = R - (float)r0, fc = C - (float)c0;
        const float* p = base + r0*SS + c0;
        float v00 = p[0], v01 = p[1], v10 = p[SS], v11 = p[SS+1];
        float top = v00 + fc*(v01-v00);
        float bot = v10 + fc*(v11-v10);
        acc += top + fr*(bot-top);
      }
    }
  }
  for (int off=32; off; off>>=1) acc += __shfl_down(acc, off);
  if (lane==0) out[gid] = acc;
}

// ---------------- ramp filter ----------------
__global__ void filter_kernel(const float* __restrict__ h0, const float* __restrict__ taps,
                              float* __restrict__ h1){
  int gid = blockIdx.x*blockDim.x + threadIdx.x;
  if (gid >= NSIN) return;
  int a = gid / DDET;
  int j = gid - a*DDET;
  const float* row = h0 + a*DDET;
  float acc = 0.f;
  for (int k=0;k<DDET;k++){
    acc += row[k] * taps[728 + j - k];
  }
  h1[gid] = acc;
}

// ---------------- backprojection ----------------
__global__ __launch_bounds__(256) void backproj_kernel(
    const float* __restrict__ h1, const float* __restrict__ trig,
    float* __restrict__ out){
  __shared__ float sh[AANG*28];
  __shared__ int   sbase[AANG];
  __shared__ float strig[2*AANG];
  int tid = threadIdx.x;
  int x0 = (blockIdx.x & 31) * 16, y0 = (blockIdx.x >> 5) * 16;
  if (tid < 2*AANG) strig[tid] = trig[tid];
  __syncthreads();
  if (tid < AANG){
    float ca = strig[tid], sa = strig[AANG+tid];
    float Xa = (float)x0 - 255.5f, Xb = Xa + 15.f;
    float Ya = (float)y0 - 255.5f, Yb = Ya + 15.f;
    float s00 = Xa*ca + Ya*sa, s01 = Xb*ca + Ya*sa;
    float s10 = Xa*ca + Yb*sa, s11 = Xb*ca + Yb*sa;
    float mn = fminf(fminf(s00,s01), fminf(s10,s11)) + 364.0f;
    sbase[tid] = (int)floorf(mn) - 2;
  }
  __syncthreads();
  for (int s = tid; s < AANG*28; s += 256){
    int a = s / 28, j = s - a*28;
    int idx = sbase[a] + j;
    sh[s] = (idx >= 0 && idx < DDET) ? h1[a*DDET + idx] : 0.f;
  }
  __syncthreads();
  int x = x0 + (tid & 15), y = y0 + (tid >> 4);
  float X = (float)x - 255.5f, Y = (float)y - 255.5f;
  float acc = 0.f;
  #pragma unroll 6
  for (int a=0;a<AANG;a++){
    float sidx = fmaf(X, strig[a], fmaf(Y, strig[AANG+a], 364.0f));
    float ff = floorf(sidx);
    int k = (int)ff - sbase[a];
    float fi = sidx - ff;
    float v0 = sh[a*28+k], v1 = sh[a*28+k+1];
    acc += v0 + fi*(v1-v0);
  }
  out[y*SS+x] = acc;
}

// ---------------- dual conv cg-split (R6-proven, global weights) ----------------
__global__ __launch_bounds__(256) void conv3x3_dualcg(
    const float* __restrict__ in1, int Cin1,
    const float* __restrict__ in2, int Cin2,
    const float* __restrict__ wt,
    const float* __restrict__ bias, const float* __restrict__ prelu,
    float* __restrict__ out)
{
  const int W = DDET, HW = NSIN;
  int pix = blockIdx.x*256 + (int)threadIdx.x;
  if (pix >= NSIN) return;
  int cg = blockIdx.y;
  int y = pix / W, x = pix - y*W;
  bool ym = y>0, yp = y<AANG-1, xm = x>0, xp = x<W-1;
  float acc[8];
  #pragma unroll
  for (int o=0;o<8;o++) acc[o] = bias[cg*8+o];
  const float* wch = wt + cg*72;
  for (int part=0; part<2; part++){
    const float* src = part ? in2 : in1;
    int nch = part ? Cin2 : Cin1;
    const float* ip = src + pix;
    for (int i=0;i<nch;i++, ip+=HW, wch+=288){
      float p4 = ip[0];
      float p0=0,p1=0,p2=0,p3=0,p5=0,p6=0,p7=0,p8=0;
      if (ym){ p1 = ip[-W]; if (xm) p0 = ip[-W-1]; if (xp) p2 = ip[-W+1]; }
      if (xm) p3 = ip[-1];
      if (xp) p5 = ip[1];
      if (yp){ p7 = ip[W]; if (xm) p6 = ip[W-1]; if (xp) p8 = ip[W+1]; }
      float p[9] = {p0,p1,p2,p3,p4,p5,p6,p7,p8};
      #pragma unroll
      for (int t=0;t<9;t++){
        float v = p[t];
        #pragma unroll
        for (int o=0;o<8;o++) acc[o] = fmaf(v, wch[t*8+o], acc[o]);
      }
    }
  }
  float aa = *prelu;
  float* op = out + (size_t)(cg*8)*HW + pix;
  #pragma unroll
  for (int o=0;o<8;o++){
    float s = acc[o];
    s = (s>=0.f) ? s : aa*s;
    op[o*HW] = s;
  }
}

// ---------------- dual conv3 (32->5): accumulate into h ----------------
template<int COUT, int W>
__global__ __launch_bounds__(256) void conv3x3_fast(
    const float* __restrict__ in1, int Cin1,
    const float* __restrict__ wt,
    const float* __restrict__ bias,
    float* __restrict__ out, int H)
{
  int HW = H*W;
  int pix = blockIdx.x*256 + (int)threadIdx.x;
  if (pix >= HW) return;
  int y = pix / W, x = pix - y*W;
  bool ym = y>0, yp = y<H-1, xm = x>0, xp = x<W-1;
  float acc[COUT];
  #pragma unroll
  for (int o=0;o<COUT;o++) acc[o] = bias[o];
  const float* wr = wt;
  const float* ip = in1 + pix;
  for (int i=0;i<Cin1;i++, ip+=HW){
    float p4 = ip[0];
    float p0=0,p1=0,p2=0,p3=0,p5=0,p6=0,p7=0,p8=0;
    if (ym){ p1 = ip[-W]; if (xm) p0 = ip[-W-1]; if (xp) p2 = ip[-W+1]; }
    if (xm) p3 = ip[-1];
    if (xp) p5 = ip[1];
    if (yp){ p7 = ip[W]; if (xm) p6 = ip[W-1]; if (xp) p8 = ip[W+1]; }
    float p[9] = {p0,p1,p2,p3,p4,p5,p6,p7,p8};
    #pragma unroll
    for (int t=0;t<9;t++){
      float v = p[t];
      #pragma unroll
      for (int o=0;o<COUT;o++) acc[o] = fmaf(v, wr[t*COUT+o], acc[o]);
    }
    wr += 9*COUT;
  }
  float* op = out + pix;
  #pragma unroll
  for (int o=0;o<COUT;o++) op[o*HW] += acc[o];
}

// ---------------- primal conv1 (6->32): R6 quad + NHWC bf16 hi/lo epilogue ----------------
__device__ inline void loadrow6(float* R, const float* p, bool valid, bool lE, bool rE){
  if (valid){
    v4u a = *(const v4u*)(p-1);
    v2a b = *(const v2a*)(p+3);
    R[0]=lE?0.f:a.x; R[1]=a.y; R[2]=a.z; R[3]=a.w;
    R[4]=b.x; R[5]=rE?0.f:b.y;
  } else {
    #pragma unroll
    for (int k=0;k<6;k++) R[k]=0.f;
  }
}

__global__ __launch_bounds__(256) void conv3x3_quad6(
    const float* __restrict__ in,      // 6 contiguous channels [f(5)|bp]
    const float* __restrict__ wt,      // [6][4][9][8]
    const float* __restrict__ bias, const float* __restrict__ prelu,
    unsigned short* __restrict__ outHi, unsigned short* __restrict__ outLo)
{
  const int W = SS, HW = NPIX;
  int rb = blockIdx.x;                       // 0..255 row-pairs
  int cg = blockIdx.y;                       // 0..3
  int yb = ((rb & 7) << 5) | (rb >> 3);      // XCD swizzle
  int wv = (int)threadIdx.x >> 6;
  int lane = (int)threadIdx.x & 63;
  int y = yb*2 + (wv >> 1);
  int xb = ((wv & 1) << 8) + lane*4;
  const float* wch = wt + cg*72;
  float acc[4][8];
  #pragma unroll
  for (int px=0;px<4;px++)
    #pragma unroll
    for (int o=0;o<8;o++) acc[px][o] = 0.f;
  bool ym = y>0, yp = y<SS-1;
  bool lE = (xb==0), rE = (xb==508);
  const float* ip = in + y*W + xb;
  for (int i=0;i<6;i++, ip+=HW, wch+=288){
    float R[3][6];
    loadrow6(R[0], ip - W, ym,   lE, rE);
    loadrow6(R[1], ip,     true, lE, rE);
    loadrow6(R[2], ip + W, yp,   lE, rE);
    #pragma unroll
    for (int dy=0;dy<3;dy++){
      #pragma unroll
      for (int dx=0;dx<3;dx++){
        #pragma unroll
        for (int o=0;o<8;o++){
          float w = wch[(dy*3+dx)*8+o];
          #pragma unroll
          for (int px=0;px<4;px++)
            acc[px][o] = fmaf(R[dy][px+dx], w, acc[px][o]);
        }
      }
    }
  }
  float aa = *prelu;
  #pragma unroll
  for (int px=0;px<4;px++){
    short8 vh, vl;
    #pragma unroll
    for (int o=0;o<8;o++){
      float s = acc[px][o] + bias[cg*8+o];
      s = (s>=0.f) ? s : aa*s;
      unsigned short hb = f2bf(s);
      float hf = __uint_as_float((unsigned)hb << 16);
      unsigned short lb = f2bf(s - hf);
      vh[o] = (short)hb; vl[o] = (short)lb;
    }
    size_t base = ((size_t)(y*W + xb + px))*32 + cg*8;
    *(short8*)(outHi + base) = vh;
    *(short8*)(outLo + base) = vl;
  }
}

// ---------------- primal conv2 (32->32): implicit-GEMM MFMA bf16 hi/lo ----------------
// Block = 4 waves, each wave: 64 px (4 m-subtiles of 16) x 32 outs (2 n-subtiles).
// K = 9 taps x 32 channels; per tap 3 products (hi*hi, lo*hi, hi*lo).
__global__ __launch_bounds__(256) void conv_mfma32(
    const unsigned short* __restrict__ hiB, const unsigned short* __restrict__ loB,
    const unsigned short* __restrict__ Bimg,   // this layer: [9][2][2][64][8]
    const float* __restrict__ bias, const float* __restrict__ prelu,
    float* __restrict__ out)
{
  int b = blockIdx.x;                 // 0..1023
  int by = b >> 1, half = b & 1;
  int y = ((by & 7) << 6) | (by >> 3);   // XCD row swizzle
  int wv = (int)threadIdx.x >> 6;
  int lane = (int)threadIdx.x & 63;
  int xw = half*256 + wv*64;
  int lm = lane & 15, lq = lane >> 4;
  int laneoff = lm*32 + lq*8;
  f32x4 acc[4][2];
  #pragma unroll
  for (int s=0;s<4;s++){ acc[s][0] = (f32x4)0.f; acc[s][1] = (f32x4)0.f; }
  bool fastx = (xw != 0) && (xw != 448);
  const short8* Bf = (const short8*)Bimg;
  #pragma unroll
  for (int dy=-1; dy<=1; dy++){
    int yy = y + dy;
    if ((unsigned)yy >= 512u) continue;
    const unsigned short* rh = hiB + (size_t)yy*512*32;
    const unsigned short* rl = loB + (size_t)yy*512*32;
    #pragma unroll
    for (int dx=-1; dx<=1; dx++){
      int tap = (dy+1)*3 + (dx+1);
      const short8* bp8 = Bf + tap*256 + lane;
      short8 bh0 = bp8[0];     // n=0 hi
      short8 bl0 = bp8[64];    // n=0 lo
      short8 bh1 = bp8[128];   // n=1 hi
      short8 bl1 = bp8[192];   // n=1 lo
      int xoff = (xw + dx)*32 + laneoff;
      #pragma unroll
      for (int s=0; s<4; s++){
        short8 ah, al;
        const unsigned short* ph = rh + xoff + s*512;
        const unsigned short* pl = rl + xoff + s*512;
        if (fastx){
          ah = *(const short8*)ph;
          al = *(const short8*)pl;
        } else {
          int x = xw + s*16 + lm + dx;
          bool ok = ((unsigned)x < 512u);
          ah = ok ? *(const short8*)ph : (short8)0;
          al = ok ? *(const short8*)pl : (short8)0;
        }
        acc[s][0] = __builtin_amdgcn_mfma_f32_16x16x32_bf16(ah, bh0, acc[s][0], 0,0,0);
        acc[s][1] = __builtin_amdgcn_mfma_f32_16x16x32_bf16(ah, bh1, acc[s][1], 0,0,0);
        acc[s][0] = __builtin_amdgcn_mfma_f32_16x16x32_bf16(al, bh0, acc[s][0], 0,0,0);
        acc[s][1] = __builtin_amdgcn_mfma_f32_16x16x32_bf16(al, bh1, acc[s][1], 0,0,0);
        acc[s][0] = __builtin_amdgcn_mfma_f32_16x16x32_bf16(ah, bl0, acc[s][0], 0,0,0);
        acc[s][1] = __builtin_amdgcn_mfma_f32_16x16x32_bf16(ah, bl1, acc[s][1], 0,0,0);
      }
    }
  }
  // epilogue: bias + prelu + planar fp32 store
  float aa = *prelu;
  #pragma unroll
  for (int s=0;s<4;s++){
    #pragma unroll
    for (int n=0;n<2;n++){
      int o = n*16 + lm;
      float bv = bias[o];
      f32x4 v = acc[s][n];
      v.x+=bv; v.y+=bv; v.z+=bv; v.w+=bv;
      v.x=(v.x>=0.f)?v.x:aa*v.x; v.y=(v.y>=0.f)?v.y:aa*v.y;
      v.z=(v.z>=0.f)?v.z:aa*v.z; v.w=(v.w>=0.f)?v.w:aa*v.w;
      *(f32x4*)(out + (size_t)o*NPIX + y*SS + xw + s*16 + lq*4) = v;
    }
  }
}

// ---------------- primal conv3 (32->5): one row per block, 2 px/thread ----------------
template<int COUT>
__global__ __launch_bounds__(256) void conv3x3_duo(
    const float* __restrict__ in1, int Cin1,
    const float* __restrict__ wt,
    const float* __restrict__ bias,
    float* __restrict__ out,
    float* __restrict__ fout, float* __restrict__ tout)
{
  const int W = SS, HW = NPIX;
  int b = blockIdx.x;
  int y = ((b & 7) << 6) | (b >> 3);
  int x0 = (int)threadIdx.x * 2;
  int pix0 = y*W + x0;
  bool ym = y > 0, yp = y < SS-1;
  bool l0 = x0 > 0;
  bool r3 = x0 + 2 < W;
  float acc0[COUT], acc1[COUT];
  #pragma unroll
  for (int o=0;o<COUT;o++){ float bv = bias[o]; acc0[o]=bv; acc1[o]=bv; }
  const float* wr = wt;
  const float* ip = in1 + pix0;
  #pragma unroll 2
  for (int i=0;i<Cin1;i++, ip+=HW){
    v4u A = ym ? *(const v4u*)(ip - W - 1) : (v4u)0.f;
    v4u B = *(const v4u*)(ip - 1);
    v4u D = yp ? *(const v4u*)(ip + W - 1) : (v4u)0.f;
    if (!l0){ A.x = 0.f; B.x = 0.f; D.x = 0.f; }
    if (!r3){ A.w = 0.f; B.w = 0.f; D.w = 0.f; }
    float w0[9] = {A.x,A.y,A.z, B.x,B.y,B.z, D.x,D.y,D.z};
    float w1[9] = {A.y,A.z,A.w, B.y,B.z,B.w, D.y,D.z,D.w};
    #pragma unroll
    for (int t=0;t<9;t++){
      float v0 = w0[t], v1 = w1[t];
      #pragma unroll
      for (int o=0;o<COUT;o++){
        float w = wr[t*COUT+o];
        acc0[o] = fmaf(v0, w, acc0[o]);
        acc1[o] = fmaf(v1, w, acc1[o]);
      }
    }
    wr += 9*COUT;
  }
  float* op = out + pix0;
  #pragma unroll
  for (int o=0;o<COUT;o++){
    float s0 = acc0[o], s1 = acc1[o];
    v2u old = *(const v2u*)(op + o*HW);
    s0 += old.x; s1 += old.y;
    v2u st; st.x = s0; st.y = s1;
    *(v2u*)(op + o*HW) = st;
    if (o==1 && tout){ tout[x0*SS + y] = s0; tout[(x0+1)*SS + y] = s1; }
    if (o==0 && fout){
      *(v2u*)(fout + pix0) = st;
      *(v2u*)(fout + HW + pix0) = st;
      *(v2u*)(fout + 2*HW + pix0) = st;
    }
  }
}

extern "C" void kernel_launch(void* const* d_in, const int* in_sizes, int n_in,
                              void* d_out, int out_size, void* d_ws, size_t ws_size,
                              hipStream_t stream){
  const float* g     = (const float*)d_in[2];
  const float* theta = (const float*)d_in[3];
  const float* dw1 = (const float*)d_in[5];
  const float* db1 = (const float*)d_in[6];
  const float* da1 = (const float*)d_in[7];
  const float* dw2 = (const float*)d_in[8];
  const float* db2 = (const float*)d_in[9];
  const float* da2 = (const float*)d_in[10];
  const float* dw3 = (const float*)d_in[11];
  const float* db3 = (const float*)d_in[12];
  const float* pw1 = (const float*)d_in[13];
  const float* pb1 = (const float*)d_in[14];
  const float* pa1 = (const float*)d_in[15];
  const float* pw2 = (const float*)d_in[16];
  const float* pb2 = (const float*)d_in[17];
  const float* pa2 = (const float*)d_in[18];
  const float* pw3 = (const float*)d_in[19];
  const float* pb3 = (const float*)d_in[20];

  float* ws     = (float*)d_ws;
  float* trig   = ws;                    // 128
  float* taps   = ws + 128;              // -> 2048
  float* h      = ws + 2048;             // 5*NSIN
  float* opf    = h + 5*NSIN;            // NSIN
  float* gcopy  = opf + NSIN;            // NSIN
  float* h1     = gcopy + NSIN;          // NSIN
  float* f      = h1 + NSIN;             // 5*NPIX
  float* bp     = f + 5*NPIX;            // NPIX
  float* imgT   = bp + NPIX;             // NPIX
  float* dualT1 = imgT + NPIX;           // 32*NSIN
  float* dualT2 = dualT1 + 32*NSIN;      // 32*NSIN
  float* primT2 = dualT2 + 32*NSIN;      // 32*NPIX
  unsigned short* nhwcHi = (unsigned short*)(primT2 + 32*NPIX);  // 32*NPIX ushorts
  unsigned short* nhwcLo = nhwcHi + (size_t)32*NPIX;             // 32*NPIX ushorts
  float* wsp   = (float*)(nhwcLo + (size_t)32*NPIX);
  float* wtd3  = wsp;                    // 14400
  float* wtp3  = wsp + 14400;            // 14400
  float* wtd1b = wsp + 28800;            // 20160
  float* wtd2b = wsp + 48960;            // 92160
  float* wtp1b = wsp + 141120;           // 17280
  unsigned short* Bimg = (unsigned short*)(wsp + 158400);  // 184320 ushorts

  hipMemsetAsync(h, 0, (size_t)(5*NSIN)*sizeof(float), stream);
  hipMemsetAsync(f, 0, (size_t)(7*NPIX)*sizeof(float), stream);   // f, bp, imgT
  hipMemcpyAsync(gcopy, g, (size_t)NSIN*sizeof(float), hipMemcpyDeviceToDevice, stream);
  trig_kernel<<<1,64,0,stream>>>(theta, trig);
  taps_kernel<<<NTAPS,256,0,stream>>>(taps);
  transpose_all<<<(28800+255)/256,256,0,stream>>>(dw3,wtd3, pw3,wtp3);
  transpose_w8<<<(20160+255)/256,256,0,stream>>>(dw1, wtd1b, 7);
  transpose_w8<<<(92160+255)/256,256,0,stream>>>(dw2, wtd2b, 32);
  transpose_w8<<<(17280+255)/256,256,0,stream>>>(pw1, wtp1b, 6);
  prep_bimg<<<(92160+255)/256,256,0,stream>>>(pw2, Bimg);

  const int GD = (NSIN+255)/256;       // 171

  for (int i=0;i<10;i++){
    radon_fwd_kernel<<<(NSIN+3)/4,256,0,stream>>>(f + NPIX, imgT, trig, opf);
    // dual block: in = [h(5) | opf | g] (opf,gcopy contiguous after h)
    conv3x3_dualcg<<<dim3(GD,4),256,0,stream>>>(h, 5, opf, 2,      wtd1b+(size_t)i*7*288,  db1+(size_t)i*32, da1+i, dualT1);
    conv3x3_dualcg<<<dim3(GD,4),256,0,stream>>>(dualT1, 32, nullptr, 0, wtd2b+(size_t)i*32*288, db2+(size_t)i*32, da2+i, dualT2);
    conv3x3_fast<5,DDET><<<GD,256,0,stream>>>(dualT2, 32, wtd3+i*1440, db3+(size_t)i*5, h, AANG);
    filter_kernel<<<GD,256,0,stream>>>(h, taps, h1);
    backproj_kernel<<<NPIX/256,256,0,stream>>>(h1, trig, bp);
    // primal block: in = [f(5) | bp] contiguous
    conv3x3_quad6<<<dim3(256,4),256,0,stream>>>(f, wtp1b+(size_t)i*6*288, pb1+(size_t)i*32, pa1+i, nhwcHi, nhwcLo);
    conv_mfma32<<<1024,256,0,stream>>>(nhwcHi, nhwcLo, Bimg+(size_t)i*18432, pb2+(size_t)i*32, pa2+i, primT2);
    conv3x3_duo<5><<<SS,256,0,stream>>>(primT2, 32, wtp3+i*1440, pb3+(size_t)i*5, f,
                                        (i==9) ? (float*)d_out : nullptr, imgT);
  }
}